// Round 1
// baseline (502.082 us; speedup 1.0000x reference)
//
#include <hip/hip_runtime.h>
#include <hip/hip_bf16.h>

// ---------- types ----------
typedef __bf16 bf16x8_t __attribute__((ext_vector_type(8)));
typedef __bf16 bf16x4_t __attribute__((ext_vector_type(4)));
typedef float  f32x4_t  __attribute__((ext_vector_type(4)));

static __device__ __forceinline__ f32x4_t mfma16(bf16x8_t a, bf16x8_t b, f32x4_t c) {
    return __builtin_amdgcn_mfma_f32_16x16x32_bf16(a, b, c, 0, 0, 0);
}

static __device__ __forceinline__ float redmax16(float v) {
#pragma unroll
    for (int off = 1; off < 16; off <<= 1) v = fmaxf(v, __shfl_xor(v, off));
    return v;
}
static __device__ __forceinline__ float redsum16(float v) {
#pragma unroll
    for (int off = 1; off < 16; off <<= 1) v += __shfl_xor(v, off);
    return v;
}

// ---------- fp32 -> bf16 convert ----------
__global__ __launch_bounds__(256) void f2b_kernel(const float* __restrict__ in,
                                                  __bf16* __restrict__ out, int n4) {
    int i = blockIdx.x * 256 + threadIdx.x;
    if (i < n4) {
        float4 v = reinterpret_cast<const float4*>(in)[i];
        bf16x4_t o;
        o[0] = (__bf16)v.x; o[1] = (__bf16)v.y; o[2] = (__bf16)v.z; o[3] = (__bf16)v.w;
        reinterpret_cast<bf16x4_t*>(out)[i] = o;
    }
}

// ---------- GEMM: C[M,N] = A[M,K] * B[N,K]^T  (bf16 in, CT out) ----------
// 128x128 tile, BK=32, 256 threads = 4 waves in 2x2 arrangement, 16x16x32 MFMA.
template <typename CT>
__global__ __launch_bounds__(256) void gemm_bt_kernel(const __bf16* __restrict__ A,
                                                      const __bf16* __restrict__ B,
                                                      CT* __restrict__ C,
                                                      int M, int N, int K) {
    __shared__ __bf16 As[128 * 32];
    __shared__ __bf16 Bs[128 * 32];

    const int t    = threadIdx.x;
    const int w    = t >> 6;
    const int lane = t & 63;
    const int quad = lane >> 4;
    const int mn   = lane & 15;
    const int wm   = (w & 1) * 64;
    const int wn   = (w >> 1) * 64;
    const long m0  = (long)blockIdx.y * 128;
    const long n0  = (long)blockIdx.x * 128;

    // staging: thread t loads 8 bf16 (16B); row = t>>2 (and +64), col8 = (t&3)*8
    const int  srow = t >> 2;
    const int  scol = (t & 3) * 8;
    const __bf16* gA = A + (m0 + srow) * (long)K + scol;
    const __bf16* gB = B + (n0 + srow) * (long)K + scol;

    f32x4_t acc[4][4];
#pragma unroll
    for (int i = 0; i < 4; i++)
#pragma unroll
        for (int j = 0; j < 4; j++) acc[i][j] = (f32x4_t){0.f, 0.f, 0.f, 0.f};

    for (int k0 = 0; k0 < K; k0 += 32) {
        bf16x8_t va0 = *(const bf16x8_t*)(gA + k0);
        bf16x8_t va1 = *(const bf16x8_t*)(gA + (long)64 * K + k0);
        bf16x8_t vb0 = *(const bf16x8_t*)(gB + k0);
        bf16x8_t vb1 = *(const bf16x8_t*)(gB + (long)64 * K + k0);
        __syncthreads();
        *(bf16x8_t*)&As[t * 8]        = va0;
        *(bf16x8_t*)&As[2048 + t * 8] = va1;
        *(bf16x8_t*)&Bs[t * 8]        = vb0;
        *(bf16x8_t*)&Bs[2048 + t * 8] = vb1;
        __syncthreads();

        bf16x8_t af[4], bf[4];
#pragma unroll
        for (int i = 0; i < 4; i++)
            af[i] = *(const bf16x8_t*)&As[(wm + i * 16 + mn) * 32 + quad * 8];
#pragma unroll
        for (int j = 0; j < 4; j++)
            bf[j] = *(const bf16x8_t*)&Bs[(wn + j * 16 + mn) * 32 + quad * 8];
#pragma unroll
        for (int i = 0; i < 4; i++)
#pragma unroll
            for (int j = 0; j < 4; j++) acc[i][j] = mfma16(af[i], bf[j], acc[i][j]);
    }

#pragma unroll
    for (int i = 0; i < 4; i++)
#pragma unroll
        for (int j = 0; j < 4; j++)
#pragma unroll
            for (int r = 0; r < 4; r++) {
                long row = m0 + wm + i * 16 + quad * 4 + r;
                long col = n0 + wn + j * 16 + mn;
                C[row * N + col] = (CT)acc[i][j][r];
            }
}

// ---------- flash attention ----------
// grid (Tq/128, H=16, B=2), 256 threads. Q tile 128 rows, S tile 64.
// Q: [B*Tq,1024], Kp: [B*S,1024], Vt: [1024, B*S], Y: [B*Tq,1024]
__global__ __launch_bounds__(256) void attn_kernel(const __bf16* __restrict__ Q,
                                                   const __bf16* __restrict__ Kp,
                                                   const __bf16* __restrict__ Vt,
                                                   const float* __restrict__ imp,
                                                   __bf16* __restrict__ Y) {
    const int qt = blockIdx.x;   // 0..15
    const int h  = blockIdx.y;   // 0..15
    const int b  = blockIdx.z;   // 0..1
    const int t    = threadIdx.x;
    const int w    = t >> 6;
    const int lane = t & 63;
    const int quad = lane >> 4;
    const int mn   = lane & 15;

    __shared__ __bf16 Qs[128][72];
    __shared__ __bf16 Ks[64][72];
    __shared__ __bf16 Vs[64][72];
    __shared__ __bf16 Ps[128][72];

    const long qrow0 = (long)b * 2048 + (long)qt * 128;

    // stage Q tile (128 x 64)
    for (int c = t; c < 1024; c += 256) {
        int r = c >> 3, col8 = (c & 7) * 8;
        *(bf16x8_t*)&Qs[r][col8] =
            *(const bf16x8_t*)&Q[(qrow0 + r) * 1024 + h * 64 + col8];
    }

    // additive mask: sensor index == (global s) & 15 == mn for 64-aligned tiles
    const float lg = logf(fmaxf(imp[b * 16 + mn], 1e-6f));

    float mrun[2][4], lrun[2][4];
#pragma unroll
    for (int rt = 0; rt < 2; rt++)
#pragma unroll
        for (int r = 0; r < 4; r++) { mrun[rt][r] = -1e30f; lrun[rt][r] = 0.f; }
    f32x4_t o[2][4];
#pragma unroll
    for (int rt = 0; rt < 2; rt++)
#pragma unroll
        for (int dt = 0; dt < 4; dt++) o[rt][dt] = (f32x4_t){0.f, 0.f, 0.f, 0.f};

    for (int s0 = 0; s0 < 4096; s0 += 64) {
        __syncthreads();
        // stage K tile (64 x 64) and V^T tile (64 x 64)
        for (int c = t; c < 512; c += 256) {
            int r = c >> 3, col8 = (c & 7) * 8;
            *(bf16x8_t*)&Ks[r][col8] =
                *(const bf16x8_t*)&Kp[((long)b * 4096 + s0 + r) * 1024 + h * 64 + col8];
        }
        for (int c = t; c < 512; c += 256) {
            int r = c >> 3, col8 = (c & 7) * 8;
            *(bf16x8_t*)&Vs[r][col8] =
                *(const bf16x8_t*)&Vt[((long)h * 64 + r) * 8192 + (long)b * 4096 + s0 + col8];
        }
        __syncthreads();

        // QK^T : per wave 32 q-rows x 64 s-cols
        f32x4_t sc[2][4];
#pragma unroll
        for (int rt = 0; rt < 2; rt++)
#pragma unroll
            for (int ct = 0; ct < 4; ct++) sc[rt][ct] = (f32x4_t){0.f, 0.f, 0.f, 0.f};

        bf16x8_t bk0[4], bk1[4];
#pragma unroll
        for (int ct = 0; ct < 4; ct++) {
            bk0[ct] = *(const bf16x8_t*)&Ks[ct * 16 + mn][quad * 8];
            bk1[ct] = *(const bf16x8_t*)&Ks[ct * 16 + mn][32 + quad * 8];
        }
#pragma unroll
        for (int rt = 0; rt < 2; rt++) {
            bf16x8_t aq0 = *(const bf16x8_t*)&Qs[w * 32 + rt * 16 + mn][quad * 8];
            bf16x8_t aq1 = *(const bf16x8_t*)&Qs[w * 32 + rt * 16 + mn][32 + quad * 8];
#pragma unroll
            for (int ct = 0; ct < 4; ct++) {
                sc[rt][ct] = mfma16(aq0, bk0[ct], sc[rt][ct]);
                sc[rt][ct] = mfma16(aq1, bk1[ct], sc[rt][ct]);
            }
        }

        // online softmax (rows live on the 16 lanes sharing a quad)
#pragma unroll
        for (int rt = 0; rt < 2; rt++) {
#pragma unroll
            for (int r = 0; r < 4; r++) {
                float s0v = sc[rt][0][r] * 0.125f + lg;
                float s1v = sc[rt][1][r] * 0.125f + lg;
                float s2v = sc[rt][2][r] * 0.125f + lg;
                float s3v = sc[rt][3][r] * 0.125f + lg;
                float mx = fmaxf(fmaxf(s0v, s1v), fmaxf(s2v, s3v));
                mx = redmax16(mx);
                float mold = mrun[rt][r];
                float mnew = fmaxf(mold, mx);
                float alpha = __expf(mold - mnew);
                float p0 = __expf(s0v - mnew);
                float p1 = __expf(s1v - mnew);
                float p2 = __expf(s2v - mnew);
                float p3 = __expf(s3v - mnew);
                float rs = redsum16(p0 + p1 + p2 + p3);
                lrun[rt][r] = lrun[rt][r] * alpha + rs;
                mrun[rt][r] = mnew;
#pragma unroll
                for (int dt = 0; dt < 4; dt++) o[rt][dt][r] *= alpha;
                int prow = w * 32 + rt * 16 + quad * 4 + r;
                Ps[prow][0  + mn] = (__bf16)p0;
                Ps[prow][16 + mn] = (__bf16)p1;
                Ps[prow][32 + mn] = (__bf16)p2;
                Ps[prow][48 + mn] = (__bf16)p3;
            }
        }
        __syncthreads();

        // PV: o += P[32x64] * V[64x64]
#pragma unroll
        for (int rt = 0; rt < 2; rt++) {
            bf16x8_t ap0 = *(const bf16x8_t*)&Ps[w * 32 + rt * 16 + mn][quad * 8];
            bf16x8_t ap1 = *(const bf16x8_t*)&Ps[w * 32 + rt * 16 + mn][32 + quad * 8];
#pragma unroll
            for (int dt = 0; dt < 4; dt++) {
                bf16x8_t bv0 = *(const bf16x8_t*)&Vs[dt * 16 + mn][quad * 8];
                bf16x8_t bv1 = *(const bf16x8_t*)&Vs[dt * 16 + mn][32 + quad * 8];
                o[rt][dt] = mfma16(ap0, bv0, o[rt][dt]);
                o[rt][dt] = mfma16(ap1, bv1, o[rt][dt]);
            }
        }
    }

    // epilogue: normalize and store merged-head Y
#pragma unroll
    for (int rt = 0; rt < 2; rt++)
#pragma unroll
        for (int r = 0; r < 4; r++) {
            float inv = 1.0f / lrun[rt][r];
            long row = qrow0 + w * 32 + rt * 16 + quad * 4 + r;
#pragma unroll
            for (int dt = 0; dt < 4; dt++)
                Y[row * 1024 + h * 64 + dt * 16 + mn] = (__bf16)(o[rt][dt][r] * inv);
        }
}

// ---------- launch ----------
extern "C" void kernel_launch(void* const* d_in, const int* in_sizes, int n_in,
                              void* d_out, int out_size, void* d_ws, size_t ws_size,
                              hipStream_t stream) {
    const float* q_f   = (const float*)d_in[0];  // [2,2048,1024]
    const float* kv_f  = (const float*)d_in[1];  // [2,256,16,1024]
    const float* imp   = (const float*)d_in[2];  // [2,16]
    const float* wq_f  = (const float*)d_in[3];
    const float* wk_f  = (const float*)d_in[4];
    const float* wv_f  = (const float*)d_in[5];
    const float* wo_f  = (const float*)d_in[6];

    char* ws = (char*)d_ws;
    size_t off = 0;
    __bf16* qb  = (__bf16*)(ws + off); off += 4194304u * 2;   // [4096,1024]
    __bf16* kvb = (__bf16*)(ws + off); off += 8388608u * 2;   // [8192,1024]
    __bf16* wqb = (__bf16*)(ws + off); off += 1048576u * 2;
    __bf16* wkb = (__bf16*)(ws + off); off += 1048576u * 2;
    __bf16* wvb = (__bf16*)(ws + off); off += 1048576u * 2;
    __bf16* wob = (__bf16*)(ws + off); off += 1048576u * 2;
    __bf16* Qp  = (__bf16*)(ws + off); off += 4194304u * 2;   // [4096,1024]
    __bf16* Kp  = (__bf16*)(ws + off); off += 8388608u * 2;   // [8192,1024]
    __bf16* Vtp = (__bf16*)(ws + off); off += 8388608u * 2;   // [1024,8192]
    __bf16* Yb  = (__bf16*)(ws + off); off += 4194304u * 2;   // [4096,1024]

    // fp32 -> bf16 conversions
    f2b_kernel<<<4096, 256, 0, stream>>>(q_f,  qb,  1048576);
    f2b_kernel<<<8192, 256, 0, stream>>>(kv_f, kvb, 2097152);
    f2b_kernel<<<1024, 256, 0, stream>>>(wq_f, wqb, 262144);
    f2b_kernel<<<1024, 256, 0, stream>>>(wk_f, wkb, 262144);
    f2b_kernel<<<1024, 256, 0, stream>>>(wv_f, wvb, 262144);
    f2b_kernel<<<1024, 256, 0, stream>>>(wo_f, wob, 262144);

    // projections
    gemm_bt_kernel<__bf16><<<dim3(8, 32), 256, 0, stream>>>(qb,  wqb, Qp,  4096, 1024, 1024);
    gemm_bt_kernel<__bf16><<<dim3(8, 64), 256, 0, stream>>>(kvb, wkb, Kp,  8192, 1024, 1024);
    // V^T = Wv * kv^T : [1024, 8192]
    gemm_bt_kernel<__bf16><<<dim3(64, 8), 256, 0, stream>>>(wvb, kvb, Vtp, 1024, 8192, 1024);

    // attention -> Yb
    attn_kernel<<<dim3(16, 16, 2), 256, 0, stream>>>(Qp, Kp, Vtp, imp, Yb);

    // output projection (fp32 out)
    gemm_bt_kernel<float><<<dim3(8, 32), 256, 0, stream>>>(Yb, wob, (float*)d_out, 4096, 1024, 1024);
}